// Round 1
// baseline (455.978 us; speedup 1.0000x reference)
//
#include <hip/hip_runtime.h>
#include <hip/hip_bf16.h>
#include <stdint.h>

// Problem dims (fixed): x [1,128,128,1024], E=1024, NH=16, D=64, M=16384.
#define MTOT 16384

typedef __attribute__((ext_vector_type(4))) float floatx4;
typedef __attribute__((ext_vector_type(8))) short shortx8;

static __device__ __forceinline__ float bf2f(unsigned short h) {
  return __uint_as_float(((unsigned int)h) << 16);
}
static __device__ __forceinline__ unsigned short f2bf(float f) {
  unsigned int u = __float_as_uint(f);
  u += 0x7fffu + ((u >> 16) & 1u);  // RNE
  return (unsigned short)(u >> 16);
}

static __device__ __forceinline__ void gload16(const void* g, void* l) {
  __builtin_amdgcn_global_load_lds(
      (const __attribute__((address_space(1))) void*)g,
      (__attribute__((address_space(3))) void*)l, 16, 0, 0);
}

// ---------------- f32 -> bf16 convert (vectorized) ----------------
__global__ __launch_bounds__(256) void cvt_f32_bf16(
    const float* __restrict__ in, unsigned short* __restrict__ out) {
  int i = (blockIdx.x * 256 + threadIdx.x) * 4;
  float4 f = *(const float4*)(in + i);
  ushort4 o;
  o.x = f2bf(f.x); o.y = f2bf(f.y); o.z = f2bf(f.z); o.w = f2bf(f.w);
  *(ushort4*)(out + i) = o;
}

// ---------------- m97-style bf16 GEMM: C = A @ BT^T ----------------
// A: [M][1024] bf16 row-major, BT: [N][1024] bf16 row-major (i.e. B^T).
// MODE 0: N=3072 (q|k|v), bias b0/b1/b2, ReLU on q,k; bf16 outputs Oq/Ok/Ov.
// MODE 1: N=1024, bias b0, f32 output Of.
template <int MODE>
__global__ __launch_bounds__(256) void gemm_bt(
    const unsigned short* __restrict__ A,
    const unsigned short* __restrict__ BT,
    const float* __restrict__ b0, const float* __restrict__ b1,
    const float* __restrict__ b2,
    unsigned short* __restrict__ Oq, unsigned short* __restrict__ Ok,
    unsigned short* __restrict__ Ov, float* __restrict__ Of) {
  __shared__ unsigned short lA[128 * 32];
  __shared__ unsigned short lB[128 * 32];
  const int K = 1024;
  const int t = threadIdx.x;
  const int m0 = blockIdx.x * 128;
  const int n0 = blockIdx.y * 128;
  const int lane = t & 63;
  const int wv = t >> 6;
  const int wm = (wv & 1) * 64;
  const int wn = (wv >> 1) * 64;
  const int mrow = lane & 15;
  const int quad = lane >> 4;

  // staging: thread t covers flat bf16 elements [t*8, t*8+8) of each 2048-elem half-tile
  const int srow = t >> 2;         // 0..63
  const int scol = (t & 3) * 8;    // 0/8/16/24
  const unsigned short* gA0 = A + (size_t)(m0 + srow) * K + scol;
  const unsigned short* gA1 = A + (size_t)(m0 + 64 + srow) * K + scol;
  const unsigned short* gB0 = BT + (size_t)(n0 + srow) * K + scol;
  const unsigned short* gB1 = BT + (size_t)(n0 + 64 + srow) * K + scol;
  unsigned short* lA0 = &lA[t * 8];
  unsigned short* lA1 = &lA[2048 + t * 8];
  unsigned short* lB0 = &lB[t * 8];
  unsigned short* lB1 = &lB[2048 + t * 8];

  floatx4 acc[4][4] = {};
  for (int kk = 0; kk < K; kk += 32) {
    gload16(gA0 + kk, lA0);
    gload16(gA1 + kk, lA1);
    gload16(gB0 + kk, lB0);
    gload16(gB1 + kk, lB1);
    __syncthreads();
    shortx8 af[4], bfr[4];
#pragma unroll
    for (int i = 0; i < 4; ++i)
      af[i] = *(const shortx8*)&lA[(wm + i * 16 + mrow) * 32 + quad * 8];
#pragma unroll
    for (int j = 0; j < 4; ++j)
      bfr[j] = *(const shortx8*)&lB[(wn + j * 16 + mrow) * 32 + quad * 8];
#pragma unroll
    for (int i = 0; i < 4; ++i)
#pragma unroll
      for (int j = 0; j < 4; ++j)
        acc[i][j] = __builtin_amdgcn_mfma_f32_16x16x32_bf16(af[i], bfr[j],
                                                            acc[i][j], 0, 0, 0);
    __syncthreads();
  }

  if (MODE == 0) {
    const int sel = n0 >> 10;  // whole 128-col block lies in one of q/k/v
    const float* bb = (sel == 0) ? b0 : ((sel == 1) ? b1 : b2);
    unsigned short* O = (sel == 0) ? Oq : ((sel == 1) ? Ok : Ov);
    const int nb = n0 & 1023;
#pragma unroll
    for (int j = 0; j < 4; ++j) {
      const int col = nb + wn + j * 16 + mrow;
      const float bias = bb[col];
#pragma unroll
      for (int i = 0; i < 4; ++i) {
#pragma unroll
        for (int r = 0; r < 4; ++r) {
          const int m = m0 + wm + i * 16 + quad * 4 + r;
          float v = acc[i][j][r] + bias;
          if (sel < 2) v = fmaxf(v, 0.0f);
          O[(size_t)m * 1024 + col] = f2bf(v);
        }
      }
    }
  } else {
#pragma unroll
    for (int j = 0; j < 4; ++j) {
      const int col = n0 + wn + j * 16 + mrow;
      const float bias = b0[col];
#pragma unroll
      for (int i = 0; i < 4; ++i) {
#pragma unroll
        for (int r = 0; r < 4; ++r) {
          const int m = m0 + wm + i * 16 + quad * 4 + r;
          Of[(size_t)m * 1024 + col] = acc[i][j][r] + bias;
        }
      }
    }
  }
}

// ---------------- kv state (VALU outer-product), stores TRANSPOSED ----------------
// axis 0: block (h,n): kvT[h][n][e][d] = sum_w K[h,w,n,d]*V[h,w,n,e]
// axis 1: block (w,n): kvT[w][n][f][e] = sum_h K[h,w,n,e]*V[h,w,n,f]
__global__ __launch_bounds__(256) void kv_state(
    const unsigned short* __restrict__ Kb, const unsigned short* __restrict__ Vb,
    unsigned short* __restrict__ kvT, int axis) {
  const int outer = blockIdx.x;
  const int n = blockIdx.y;
  __shared__ unsigned short lK[128 * 64];
  __shared__ unsigned short lV[128 * 64];
  const int t = threadIdx.x;
  const size_t base = (axis == 0) ? ((size_t)outer << 17) : ((size_t)outer << 10);
  const size_t istr = (axis == 0) ? (size_t)1024 : (size_t)131072;
#pragma unroll
  for (int it = 0; it < 4; ++it) {
    const int f = (it * 256 + t) * 8;
    const int inner = f >> 6;
    const int d0 = f & 63;
    const size_t g = base + (size_t)inner * istr + (n << 6) + d0;
    *(uint4*)&lK[f] = *(const uint4*)&Kb[g];
    *(uint4*)&lV[f] = *(const uint4*)&Vb[g];
  }
  __syncthreads();
  const int e = t >> 2;          // broadcast index (V)
  const int d0 = (t & 3) * 16;   // 16-wide slice of K
  float acc[16] = {0, 0, 0, 0, 0, 0, 0, 0, 0, 0, 0, 0, 0, 0, 0, 0};
#pragma unroll 2
  for (int w = 0; w < 128; ++w) {
    const float ve = bf2f(lV[w * 64 + e]);
    shortx8 k0 = *(const shortx8*)&lK[w * 64 + d0];
    shortx8 k1 = *(const shortx8*)&lK[w * 64 + d0 + 8];
#pragma unroll
    for (int i = 0; i < 8; ++i) acc[i] += ve * bf2f((unsigned short)k0[i]);
#pragma unroll
    for (int i = 0; i < 8; ++i) acc[8 + i] += ve * bf2f((unsigned short)k1[i]);
  }
  unsigned short ov[16];
#pragma unroll
  for (int i = 0; i < 16; ++i) ov[i] = f2bf(acc[i]);
  const size_t o = (((size_t)outer * 16 + n) << 12) + ((size_t)e << 6) + d0;
  *(uint4*)&kvT[o] = *(const uint4*)&ov[0];
  *(uint4*)&kvT[o + 8] = *(const uint4*)&ov[8];
}

// ---------------- apply state (MFMA): D[row][col] = sum_c S[row][c]*KV[c][col] ----------------
// kvT stored transposed [col][c] so B-fragments read contiguously.
// axis 0: block (h,n), rows = w. axis 1: block (w,n), rows = h.
__global__ __launch_bounds__(256) void apply_state(
    const unsigned short* __restrict__ S, const unsigned short* __restrict__ kvT,
    unsigned short* __restrict__ D, int axis) {
  const int outer = blockIdx.x;
  const int n = blockIdx.y;
  __shared__ unsigned short lA[128 * 72];  // padded: 72*2=144B stride -> no conflicts
  __shared__ unsigned short lB[64 * 72];
  const int t = threadIdx.x;
  const size_t base = (axis == 0) ? ((size_t)outer << 17) : ((size_t)outer << 10);
  const size_t istr = (axis == 0) ? (size_t)1024 : (size_t)131072;
#pragma unroll
  for (int it = 0; it < 4; ++it) {
    const int f = (it * 256 + t) * 8;
    const int inner = f >> 6;
    const int d0 = f & 63;
    const size_t g = base + (size_t)inner * istr + (n << 6) + d0;
    uint4 val = *(const uint4*)&S[g];
    *(uint4*)&lA[inner * 72 + d0] = val;
  }
  const size_t kvbase = (((size_t)outer * 16 + n) << 12);
#pragma unroll
  for (int it = 0; it < 2; ++it) {
    const int f = (it * 256 + t) * 8;
    const int e = f >> 6;
    const int d0 = f & 63;
    uint4 val = *(const uint4*)&kvT[kvbase + f];
    *(uint4*)&lB[e * 72 + d0] = val;
  }
  __syncthreads();
  const int lane = t & 63;
  const int wv = t >> 6;
  const int wm = wv * 32;
  const int mrow = lane & 15;
  const int quad = lane >> 4;
  floatx4 acc[2][4] = {};
#pragma unroll
  for (int ks = 0; ks < 64; ks += 32) {
    shortx8 af[2], bfr[4];
#pragma unroll
    for (int i = 0; i < 2; ++i)
      af[i] = *(const shortx8*)&lA[(wm + i * 16 + mrow) * 72 + ks + quad * 8];
#pragma unroll
    for (int j = 0; j < 4; ++j)
      bfr[j] = *(const shortx8*)&lB[(j * 16 + mrow) * 72 + ks + quad * 8];
#pragma unroll
    for (int i = 0; i < 2; ++i)
#pragma unroll
      for (int j = 0; j < 4; ++j)
        acc[i][j] = __builtin_amdgcn_mfma_f32_16x16x32_bf16(af[i], bfr[j],
                                                            acc[i][j], 0, 0, 0);
  }
#pragma unroll
  for (int i = 0; i < 2; ++i) {
#pragma unroll
    for (int j = 0; j < 4; ++j) {
      const int col = j * 16 + mrow;
#pragma unroll
      for (int r = 0; r < 4; ++r) {
        const int row = wm + i * 16 + quad * 4 + r;
        const size_t g = base + (size_t)row * istr + (n << 6) + col;
        D[g] = f2bf(acc[i][j][r]);
      }
    }
  }
}

extern "C" void kernel_launch(void* const* d_in, const int* in_sizes, int n_in,
                              void* d_out, int out_size, void* d_ws, size_t ws_size,
                              hipStream_t stream) {
  const float* x  = (const float*)d_in[0];
  const float* Wq = (const float*)d_in[1];
  const float* bq = (const float*)d_in[2];
  const float* Wk = (const float*)d_in[3];
  const float* bk = (const float*)d_in[4];
  const float* Wv = (const float*)d_in[5];
  const float* bv = (const float*)d_in[6];
  const float* Wo = (const float*)d_in[7];
  const float* bo = (const float*)d_in[8];
  float* out = (float*)d_out;

  char* ws = (char*)d_ws;
  unsigned short* xb    = (unsigned short*)(ws + 0);          // 16M elem (33.5MB)
  unsigned short* wqkvb = (unsigned short*)(ws + 33554432);   // 3M elem
  unsigned short* wob   = (unsigned short*)(ws + 39845888);   // 1M elem
  unsigned short* qb    = (unsigned short*)(ws + 41943040);   // 16M elem
  unsigned short* kb    = (unsigned short*)(ws + 75497472);   // 16M elem
  unsigned short* vb    = (unsigned short*)(ws + 109051904);  // 16M elem
  unsigned short* kvwT  = (unsigned short*)(ws + 142606336);  // 8M elem
  unsigned short* kvhT  = (unsigned short*)(ws + 159383552);  // 8M elem
  unsigned short* out1  = xb;  // reuse: x not needed after projections
  unsigned short* out2  = qb;  // reuse: q not needed after apply_w

  // 1) converts to bf16
  cvt_f32_bf16<<<dim3(16384), dim3(256), 0, stream>>>(x, xb);
  cvt_f32_bf16<<<dim3(1024), dim3(256), 0, stream>>>(Wq, wqkvb);
  cvt_f32_bf16<<<dim3(1024), dim3(256), 0, stream>>>(Wk, wqkvb + 1048576);
  cvt_f32_bf16<<<dim3(1024), dim3(256), 0, stream>>>(Wv, wqkvb + 2097152);
  cvt_f32_bf16<<<dim3(1024), dim3(256), 0, stream>>>(Wo, wob);
  // 2) fused QKV projection (+bias, ReLU on q,k)
  gemm_bt<0><<<dim3(128, 24), dim3(256), 0, stream>>>(
      xb, wqkvb, bq, bk, bv, qb, kb, vb, (float*)nullptr);
  // 3) kv states (transposed)
  kv_state<<<dim3(128, 16), dim3(256), 0, stream>>>(kb, vb, kvwT, 0);
  kv_state<<<dim3(128, 16), dim3(256), 0, stream>>>(kb, vb, kvhT, 1);
  // 4) applies
  apply_state<<<dim3(128, 16), dim3(256), 0, stream>>>(qb, kvwT, out1, 0);
  apply_state<<<dim3(128, 16), dim3(256), 0, stream>>>(out1, kvhT, out2, 1);
  // 5) output projection (+bias), fp32 out
  gemm_bt<1><<<dim3(128, 8), dim3(256), 0, stream>>>(
      out2, wob, bo, nullptr, nullptr, nullptr, nullptr, nullptr, out);
}

// Round 2
// 360.959 us; speedup vs baseline: 1.2632x; 1.2632x over previous
//
#include <hip/hip_runtime.h>
#include <hip/hip_bf16.h>
#include <stdint.h>

// Problem dims (fixed): x [1,128,128,1024], E=1024, NH=16, D=64, M=16384.

typedef __attribute__((ext_vector_type(4))) float floatx4;
typedef __attribute__((ext_vector_type(8))) short shortx8;

static __device__ __forceinline__ float bf2f(unsigned short h) {
  return __uint_as_float(((unsigned int)h) << 16);
}
static __device__ __forceinline__ unsigned short f2bf(float f) {
  unsigned int u = __float_as_uint(f);
  u += 0x7fffu + ((u >> 16) & 1u);  // RNE
  return (unsigned short)(u >> 16);
}

static __device__ __forceinline__ void gload16(const void* g, void* l) {
  __builtin_amdgcn_global_load_lds(
      (const __attribute__((address_space(1))) void*)g,
      (__attribute__((address_space(3))) void*)l, 16, 0, 0);
}

// ---------------- merged f32 -> bf16 convert ----------------
// blocks [0,16384): x; [16384,17408): Wq; [17408,18432): Wk;
// [18432,19456): Wv; [19456,20480): Wo.
__global__ __launch_bounds__(256) void cvt_all(
    const float* __restrict__ x, const float* __restrict__ Wq,
    const float* __restrict__ Wk, const float* __restrict__ Wv,
    const float* __restrict__ Wo, unsigned short* __restrict__ xb,
    unsigned short* __restrict__ wqkvb, unsigned short* __restrict__ wob) {
  const int b = blockIdx.x;
  const float* src;
  unsigned short* dst;
  int off;
  if (b < 16384) {
    src = x; dst = xb; off = b;
  } else if (b < 17408) {
    src = Wq; dst = wqkvb; off = b - 16384;
  } else if (b < 18432) {
    src = Wk; dst = wqkvb + 1048576; off = b - 17408;
  } else if (b < 19456) {
    src = Wv; dst = wqkvb + 2097152; off = b - 18432;
  } else {
    src = Wo; dst = wob; off = b - 19456;
  }
  const int i = (off * 256 + threadIdx.x) * 4;
  float4 f = *(const float4*)(src + i);
  ushort4 o;
  o.x = f2bf(f.x); o.y = f2bf(f.y); o.z = f2bf(f.z); o.w = f2bf(f.w);
  *(ushort4*)(dst + i) = o;
}

// ---------------- m97-style bf16 GEMM: C = A @ BT^T ----------------
// A: [M][1024] bf16 row-major, BT: [N][1024] bf16 row-major (i.e. B^T).
// MODE 0: N=3072 (q|k|v), bias b0/b1/b2, ReLU on q,k; bf16 outputs Oq/Ok/Ov.
// MODE 1: N=1024, bias b0, f32 output Of.
template <int MODE>
__global__ __launch_bounds__(256) void gemm_bt(
    const unsigned short* __restrict__ A,
    const unsigned short* __restrict__ BT,
    const float* __restrict__ b0, const float* __restrict__ b1,
    const float* __restrict__ b2,
    unsigned short* __restrict__ Oq, unsigned short* __restrict__ Ok,
    unsigned short* __restrict__ Ov, float* __restrict__ Of) {
  __shared__ unsigned short lA[128 * 32];
  __shared__ unsigned short lB[128 * 32];
  const int K = 1024;
  const int t = threadIdx.x;
  const int m0 = blockIdx.x * 128;
  const int n0 = blockIdx.y * 128;
  const int lane = t & 63;
  const int wv = t >> 6;
  const int wm = (wv & 1) * 64;
  const int wn = (wv >> 1) * 64;
  const int mrow = lane & 15;
  const int quad = lane >> 4;

  const int srow = t >> 2;
  const int scol = (t & 3) * 8;
  const unsigned short* gA0 = A + (size_t)(m0 + srow) * K + scol;
  const unsigned short* gA1 = A + (size_t)(m0 + 64 + srow) * K + scol;
  const unsigned short* gB0 = BT + (size_t)(n0 + srow) * K + scol;
  const unsigned short* gB1 = BT + (size_t)(n0 + 64 + srow) * K + scol;
  unsigned short* lA0 = &lA[t * 8];
  unsigned short* lA1 = &lA[2048 + t * 8];
  unsigned short* lB0 = &lB[t * 8];
  unsigned short* lB1 = &lB[2048 + t * 8];

  floatx4 acc[4][4] = {};
  for (int kk = 0; kk < K; kk += 32) {
    gload16(gA0 + kk, lA0);
    gload16(gA1 + kk, lA1);
    gload16(gB0 + kk, lB0);
    gload16(gB1 + kk, lB1);
    __syncthreads();
    shortx8 af[4], bfr[4];
#pragma unroll
    for (int i = 0; i < 4; ++i)
      af[i] = *(const shortx8*)&lA[(wm + i * 16 + mrow) * 32 + quad * 8];
#pragma unroll
    for (int j = 0; j < 4; ++j)
      bfr[j] = *(const shortx8*)&lB[(wn + j * 16 + mrow) * 32 + quad * 8];
#pragma unroll
    for (int i = 0; i < 4; ++i)
#pragma unroll
      for (int j = 0; j < 4; ++j)
        acc[i][j] = __builtin_amdgcn_mfma_f32_16x16x32_bf16(af[i], bfr[j],
                                                            acc[i][j], 0, 0, 0);
    __syncthreads();
  }

  if (MODE == 0) {
    const int sel = n0 >> 10;
    const float* bb = (sel == 0) ? b0 : ((sel == 1) ? b1 : b2);
    unsigned short* O = (sel == 0) ? Oq : ((sel == 1) ? Ok : Ov);
    const int nb = n0 & 1023;
#pragma unroll
    for (int j = 0; j < 4; ++j) {
      const int col = nb + wn + j * 16 + mrow;
      const float bias = bb[col];
#pragma unroll
      for (int i = 0; i < 4; ++i) {
#pragma unroll
        for (int r = 0; r < 4; ++r) {
          const int m = m0 + wm + i * 16 + quad * 4 + r;
          float v = acc[i][j][r] + bias;
          if (sel < 2) v = fmaxf(v, 0.0f);
          O[(size_t)m * 1024 + col] = f2bf(v);
        }
      }
    }
  } else {
#pragma unroll
    for (int j = 0; j < 4; ++j) {
      const int col = n0 + wn + j * 16 + mrow;
      const float bias = b0[col];
#pragma unroll
      for (int i = 0; i < 4; ++i) {
#pragma unroll
        for (int r = 0; r < 4; ++r) {
          const int m = m0 + wm + i * 16 + quad * 4 + r;
          Of[(size_t)m * 1024 + col] = acc[i][j][r] + bias;
        }
      }
    }
  }
}

// ---------------- fused retention (one axis): out = S @ (K^T V) per (outer, head)
// axis 0: block (h, n), inner index w (row stride 1024 elem).
// axis 1: block (w, n), inner index h (row stride 131072 elem).
// Stage 1 (MFMA): lKV[e][d] = sum_i V[i,e] * K[i,d]  (= kv[d][e], stored transposed)
// Stage 2 (MFMA): out[r][e] = sum_d S[r,d] * kv[d][e]
__global__ __launch_bounds__(256) void retention_fused(
    const unsigned short* __restrict__ S, const unsigned short* __restrict__ Kb,
    const unsigned short* __restrict__ Vb, unsigned short* __restrict__ D,
    int axis) {
  const int outer = blockIdx.x;
  const int n = blockIdx.y;
  __shared__ unsigned short lS[128 * 72];    // row-major, pad to 72
  __shared__ unsigned short lKT[64 * 136];   // K transposed [d][i], pad to 136
  __shared__ unsigned short lVT[64 * 136];   // V transposed [e][i]
  __shared__ unsigned short lKV[64 * 72];    // kv^T [e][d], pad to 72
  const int t = threadIdx.x;
  const size_t base = (axis == 0) ? ((size_t)outer << 17) : ((size_t)outer << 10);
  const size_t istr = (axis == 0) ? (size_t)1024 : (size_t)131072;
  const size_t nof = (size_t)(n << 6);

  // S: row-major coalesced load, padded store
#pragma unroll
  for (int it = 0; it < 4; ++it) {
    const int r = it * 32 + (t >> 3);
    const int c = (t & 7) * 8;
    uint4 v = *(const uint4*)&S[base + (size_t)r * istr + nof + c];
    *(uint4*)&lS[r * 72 + c] = v;
  }
  // K, V: transposed store (i in low lane bits so LDS writes spread banks)
#pragma unroll
  for (int it = 0; it < 4; ++it) {
    const int w = it * 32 + (t & 31);
    const int d0 = (t >> 5) * 8;
    const size_t g = base + (size_t)w * istr + nof + d0;
    uint4 k4 = *(const uint4*)&Kb[g];
    uint4 v4 = *(const uint4*)&Vb[g];
    const unsigned short* kp = (const unsigned short*)&k4;
    const unsigned short* vp = (const unsigned short*)&v4;
#pragma unroll
    for (int i = 0; i < 8; ++i) {
      lKT[(d0 + i) * 136 + w] = kp[i];
      lVT[(d0 + i) * 136 + w] = vp[i];
    }
  }
  __syncthreads();

  const int lane = t & 63;
  const int wv = t >> 6;
  const int mrow = lane & 15;
  const int quad = lane >> 4;

  // Stage 1: wave wv computes e-tile wv (rows e=wv*16..+15 of lKV), all 4 d-tiles
  floatx4 acc1[4] = {};
#pragma unroll
  for (int ks = 0; ks < 4; ++ks) {
    shortx8 a = *(const shortx8*)&lVT[(wv * 16 + mrow) * 136 + ks * 32 + quad * 8];
#pragma unroll
    for (int j = 0; j < 4; ++j) {
      shortx8 b = *(const shortx8*)&lKT[(j * 16 + mrow) * 136 + ks * 32 + quad * 8];
      acc1[j] = __builtin_amdgcn_mfma_f32_16x16x32_bf16(a, b, acc1[j], 0, 0, 0);
    }
  }
#pragma unroll
  for (int j = 0; j < 4; ++j)
#pragma unroll
    for (int r = 0; r < 4; ++r)
      lKV[(wv * 16 + quad * 4 + r) * 72 + j * 16 + mrow] = f2bf(acc1[j][r]);
  __syncthreads();

  // Stage 2: wave wv computes rows [wv*32, wv*32+32)
  floatx4 acc2[2][4] = {};
#pragma unroll
  for (int ks = 0; ks < 2; ++ks) {
    shortx8 a2[2], b2[4];
#pragma unroll
    for (int i = 0; i < 2; ++i)
      a2[i] = *(const shortx8*)&lS[(wv * 32 + i * 16 + mrow) * 72 + ks * 32 + quad * 8];
#pragma unroll
    for (int j = 0; j < 4; ++j)
      b2[j] = *(const shortx8*)&lKV[(j * 16 + mrow) * 72 + ks * 32 + quad * 8];
#pragma unroll
    for (int i = 0; i < 2; ++i)
#pragma unroll
      for (int j = 0; j < 4; ++j)
        acc2[i][j] = __builtin_amdgcn_mfma_f32_16x16x32_bf16(a2[i], b2[j],
                                                             acc2[i][j], 0, 0, 0);
  }
#pragma unroll
  for (int i = 0; i < 2; ++i)
#pragma unroll
    for (int j = 0; j < 4; ++j)
#pragma unroll
      for (int r = 0; r < 4; ++r) {
        const int row = wv * 32 + i * 16 + quad * 4 + r;
        const int col = j * 16 + mrow;
        D[base + (size_t)row * istr + nof + col] = f2bf(acc2[i][j][r]);
      }
}

extern "C" void kernel_launch(void* const* d_in, const int* in_sizes, int n_in,
                              void* d_out, int out_size, void* d_ws, size_t ws_size,
                              hipStream_t stream) {
  const float* x  = (const float*)d_in[0];
  const float* Wq = (const float*)d_in[1];
  const float* bq = (const float*)d_in[2];
  const float* Wk = (const float*)d_in[3];
  const float* bk = (const float*)d_in[4];
  const float* Wv = (const float*)d_in[5];
  const float* bv = (const float*)d_in[6];
  const float* Wo = (const float*)d_in[7];
  const float* bo = (const float*)d_in[8];
  float* out = (float*)d_out;

  char* ws = (char*)d_ws;
  unsigned short* xb    = (unsigned short*)(ws + 0);          // 16M elem
  unsigned short* wqkvb = (unsigned short*)(ws + 33554432);   // 3M elem
  unsigned short* wob   = (unsigned short*)(ws + 39845888);   // 1M elem
  unsigned short* qb    = (unsigned short*)(ws + 41943040);   // 16M elem
  unsigned short* kb    = (unsigned short*)(ws + 75497472);   // 16M elem
  unsigned short* vb    = (unsigned short*)(ws + 109051904);  // 16M elem
  unsigned short* out1  = xb;  // reuse: x not needed after projections
  unsigned short* out2  = qb;  // reuse: q not needed after axis-0 retention

  // 1) merged converts (1 launch instead of 5)
  cvt_all<<<dim3(20480), dim3(256), 0, stream>>>(x, Wq, Wk, Wv, Wo, xb, wqkvb, wob);
  // 2) fused QKV projection (+bias, ReLU on q,k)
  gemm_bt<0><<<dim3(128, 24), dim3(256), 0, stream>>>(
      xb, wqkvb, bq, bk, bv, qb, kb, vb, (float*)nullptr);
  // 3) width-axis retention (kv + apply fused)
  retention_fused<<<dim3(128, 16), dim3(256), 0, stream>>>(qb, kb, vb, out1, 0);
  // 4) height-axis retention
  retention_fused<<<dim3(128, 16), dim3(256), 0, stream>>>(out1, kb, vb, out2, 1);
  // 5) output projection (+bias), fp32 out
  gemm_bt<1><<<dim3(128, 8), dim3(256), 0, stream>>>(
      out2, wob, bo, nullptr, nullptr, nullptr, nullptr, nullptr, out);
}

// Round 3
// 354.820 us; speedup vs baseline: 1.2851x; 1.0173x over previous
//
#include <hip/hip_runtime.h>
#include <hip/hip_bf16.h>
#include <stdint.h>

// Problem dims (fixed): x [1,128,128,1024], E=1024, NH=16, D=64, M=16384.

typedef __attribute__((ext_vector_type(4))) float floatx4;
typedef __attribute__((ext_vector_type(8))) short shortx8;

static __device__ __forceinline__ float bf2f(unsigned short h) {
  return __uint_as_float(((unsigned int)h) << 16);
}
static __device__ __forceinline__ unsigned short f2bf(float f) {
  unsigned int u = __float_as_uint(f);
  u += 0x7fffu + ((u >> 16) & 1u);  // RNE
  return (unsigned short)(u >> 16);
}

static __device__ __forceinline__ void gload16(const void* g, void* l) {
  __builtin_amdgcn_global_load_lds(
      (const __attribute__((address_space(1))) void*)g,
      (__attribute__((address_space(3))) void*)l, 16, 0, 0);
}

// ---------------- merged f32 -> bf16 convert ----------------
__global__ __launch_bounds__(256) void cvt_all(
    const float* __restrict__ x, const float* __restrict__ Wq,
    const float* __restrict__ Wk, const float* __restrict__ Wv,
    const float* __restrict__ Wo, unsigned short* __restrict__ xb,
    unsigned short* __restrict__ wqkvb, unsigned short* __restrict__ wob) {
  const int b = blockIdx.x;
  const float* src;
  unsigned short* dst;
  int off;
  if (b < 16384) {
    src = x; dst = xb; off = b;
  } else if (b < 17408) {
    src = Wq; dst = wqkvb; off = b - 16384;
  } else if (b < 18432) {
    src = Wk; dst = wqkvb + 1048576; off = b - 17408;
  } else if (b < 19456) {
    src = Wv; dst = wqkvb + 2097152; off = b - 18432;
  } else {
    src = Wo; dst = wob; off = b - 19456;
  }
  const int i = (off * 256 + threadIdx.x) * 4;
  float4 f = *(const float4*)(src + i);
  ushort4 o;
  o.x = f2bf(f.x); o.y = f2bf(f.y); o.z = f2bf(f.z); o.w = f2bf(f.w);
  *(ushort4*)(dst + i) = o;
}

// ---------------- m97-style bf16 GEMM with XOR-swizzled LDS: C = A @ BT^T ----
// Swizzle: staging lane t loads global k-chunk ((t&3) ^ ((srow>>1)&3)) so that
// fragment reads at slot (quad ^ ((mrow>>1)&3)) cover all 8 16B bank positions
// exactly twice per 16-lane phase (2-way = free) instead of 8-way.
// MODE 0: N=3072 (q|k|v), bias b0/b1/b2, ReLU on q,k; bf16 out, LDS-transposed
//         vectorized epilogue (16B stores).
// MODE 1: N=1024, bias b0, f32 out, scalar epilogue.
template <int MODE>
__global__ __launch_bounds__(256) void gemm_bt(
    const unsigned short* __restrict__ A,
    const unsigned short* __restrict__ BT,
    const float* __restrict__ b0, const float* __restrict__ b1,
    const float* __restrict__ b2,
    unsigned short* __restrict__ Oq, unsigned short* __restrict__ Ok,
    unsigned short* __restrict__ Ov, float* __restrict__ Of) {
  // 36,864 B shared: K-loop uses first 16 KiB (lA|lB); epilogue reuses all of
  // it as 4 per-wave 64x72 transpose tiles.
  __shared__ __align__(16) unsigned short smem[18432];
  unsigned short* lA = smem;         // 128*32
  unsigned short* lB = smem + 4096;  // 128*32
  const int K = 1024;
  const int t = threadIdx.x;
  const int m0 = blockIdx.x * 128;
  const int n0 = blockIdx.y * 128;
  const int lane = t & 63;
  const int wv = t >> 6;
  const int wm = (wv & 1) * 64;
  const int wn = (wv >> 1) * 64;
  const int mrow = lane & 15;
  const int quad = lane >> 4;
  const int slot = quad ^ ((mrow >> 1) & 3);  // swizzled fragment slot

  const int srow = t >> 2;
  const int scol = (((t & 3) ^ ((srow >> 1) & 3))) * 8;  // swizzled stage chunk
  const unsigned short* gA0 = A + (size_t)(m0 + srow) * K + scol;
  const unsigned short* gA1 = A + (size_t)(m0 + 64 + srow) * K + scol;
  const unsigned short* gB0 = BT + (size_t)(n0 + srow) * K + scol;
  const unsigned short* gB1 = BT + (size_t)(n0 + 64 + srow) * K + scol;
  unsigned short* lA0 = &lA[t * 8];
  unsigned short* lA1 = &lA[2048 + t * 8];
  unsigned short* lB0 = &lB[t * 8];
  unsigned short* lB1 = &lB[2048 + t * 8];

  floatx4 acc[4][4] = {};
  for (int kk = 0; kk < K; kk += 32) {
    gload16(gA0 + kk, lA0);
    gload16(gA1 + kk, lA1);
    gload16(gB0 + kk, lB0);
    gload16(gB1 + kk, lB1);
    __syncthreads();
    shortx8 af[4], bfr[4];
#pragma unroll
    for (int i = 0; i < 4; ++i)
      af[i] = *(const shortx8*)&lA[(wm + i * 16 + mrow) * 32 + slot * 8];
#pragma unroll
    for (int j = 0; j < 4; ++j)
      bfr[j] = *(const shortx8*)&lB[(wn + j * 16 + mrow) * 32 + slot * 8];
#pragma unroll
    for (int i = 0; i < 4; ++i)
#pragma unroll
      for (int j = 0; j < 4; ++j)
        acc[i][j] = __builtin_amdgcn_mfma_f32_16x16x32_bf16(af[i], bfr[j],
                                                            acc[i][j], 0, 0, 0);
    __syncthreads();
  }

  if (MODE == 0) {
    const int sel = n0 >> 10;
    const float* bb = (sel == 0) ? b0 : ((sel == 1) ? b1 : b2);
    unsigned short* O = (sel == 0) ? Oq : ((sel == 1) ? Ok : Ov);
    const int nb = n0 & 1023;
    // Stage bias/relu'd bf16 into per-wave 64x72 LDS tile (pad 72 elem =
    // 144 B row stride -> readback positions (row+chunk)%8 conflict-free).
    unsigned short* we = smem + wv * 4608;
#pragma unroll
    for (int j = 0; j < 4; ++j) {
      const int coll = j * 16 + mrow;
      const float bias = bb[nb + wn + coll];
#pragma unroll
      for (int i = 0; i < 4; ++i) {
#pragma unroll
        for (int r = 0; r < 4; ++r) {
          const int rowl = i * 16 + quad * 4 + r;
          float v = acc[i][j][r] + bias;
          if (sel < 2) v = fmaxf(v, 0.0f);
          we[rowl * 72 + coll] = f2bf(v);
        }
      }
    }
    __syncthreads();
    const int r8 = lane >> 3;  // 0..7
    const int c8 = lane & 7;   // 0..7
#pragma unroll
    for (int p = 0; p < 8; ++p) {
      const int rowl = r8 + p * 8;
      uint4 v = *(const uint4*)&we[rowl * 72 + c8 * 8];
      *(uint4*)&O[(size_t)(m0 + wm + rowl) * 1024 + nb + wn + c8 * 8] = v;
    }
  } else {
#pragma unroll
    for (int j = 0; j < 4; ++j) {
      const int col = n0 + wn + j * 16 + mrow;
      const float bias = b0[col];
#pragma unroll
      for (int i = 0; i < 4; ++i) {
#pragma unroll
        for (int r = 0; r < 4; ++r) {
          const int m = m0 + wm + i * 16 + quad * 4 + r;
          Of[(size_t)m * 1024 + col] = acc[i][j][r] + bias;
        }
      }
    }
  }
}

// ---------------- fused retention (one axis): out = S @ (K^T V) per (outer, head)
__global__ __launch_bounds__(256) void retention_fused(
    const unsigned short* __restrict__ S, const unsigned short* __restrict__ Kb,
    const unsigned short* __restrict__ Vb, unsigned short* __restrict__ D,
    int axis) {
  const int outer = blockIdx.x;
  const int n = blockIdx.y;
  __shared__ unsigned short lS[128 * 72];
  __shared__ unsigned short lKT[64 * 136];
  __shared__ unsigned short lVT[64 * 136];
  __shared__ unsigned short lKV[64 * 72];
  const int t = threadIdx.x;
  const size_t base = (axis == 0) ? ((size_t)outer << 17) : ((size_t)outer << 10);
  const size_t istr = (axis == 0) ? (size_t)1024 : (size_t)131072;
  const size_t nof = (size_t)(n << 6);

#pragma unroll
  for (int it = 0; it < 4; ++it) {
    const int r = it * 32 + (t >> 3);
    const int c = (t & 7) * 8;
    uint4 v = *(const uint4*)&S[base + (size_t)r * istr + nof + c];
    *(uint4*)&lS[r * 72 + c] = v;
  }
#pragma unroll
  for (int it = 0; it < 4; ++it) {
    const int w = it * 32 + (t & 31);
    const int d0 = (t >> 5) * 8;
    const size_t g = base + (size_t)w * istr + nof + d0;
    uint4 k4 = *(const uint4*)&Kb[g];
    uint4 v4 = *(const uint4*)&Vb[g];
    const unsigned short* kp = (const unsigned short*)&k4;
    const unsigned short* vp = (const unsigned short*)&v4;
#pragma unroll
    for (int i = 0; i < 8; ++i) {
      lKT[(d0 + i) * 136 + w] = kp[i];
      lVT[(d0 + i) * 136 + w] = vp[i];
    }
  }
  __syncthreads();

  const int lane = t & 63;
  const int wv = t >> 6;
  const int mrow = lane & 15;
  const int quad = lane >> 4;

  floatx4 acc1[4] = {};
#pragma unroll
  for (int ks = 0; ks < 4; ++ks) {
    shortx8 a = *(const shortx8*)&lVT[(wv * 16 + mrow) * 136 + ks * 32 + quad * 8];
#pragma unroll
    for (int j = 0; j < 4; ++j) {
      shortx8 b = *(const shortx8*)&lKT[(j * 16 + mrow) * 136 + ks * 32 + quad * 8];
      acc1[j] = __builtin_amdgcn_mfma_f32_16x16x32_bf16(a, b, acc1[j], 0, 0, 0);
    }
  }
#pragma unroll
  for (int j = 0; j < 4; ++j)
#pragma unroll
    for (int r = 0; r < 4; ++r)
      lKV[(wv * 16 + quad * 4 + r) * 72 + j * 16 + mrow] = f2bf(acc1[j][r]);
  __syncthreads();

  floatx4 acc2[2][4] = {};
#pragma unroll
  for (int ks = 0; ks < 2; ++ks) {
    shortx8 a2[2], b2[4];
#pragma unroll
    for (int i = 0; i < 2; ++i)
      a2[i] = *(const shortx8*)&lS[(wv * 32 + i * 16 + mrow) * 72 + ks * 32 + quad * 8];
#pragma unroll
    for (int j = 0; j < 4; ++j)
      b2[j] = *(const shortx8*)&lKV[(j * 16 + mrow) * 72 + ks * 32 + quad * 8];
#pragma unroll
    for (int i = 0; i < 2; ++i)
#pragma unroll
      for (int j = 0; j < 4; ++j)
        acc2[i][j] = __builtin_amdgcn_mfma_f32_16x16x32_bf16(a2[i], b2[j],
                                                             acc2[i][j], 0, 0, 0);
  }
#pragma unroll
  for (int i = 0; i < 2; ++i)
#pragma unroll
    for (int j = 0; j < 4; ++j)
#pragma unroll
      for (int r = 0; r < 4; ++r) {
        const int row = wv * 32 + i * 16 + quad * 4 + r;
        const int col = j * 16 + mrow;
        D[base + (size_t)row * istr + nof + col] = f2bf(acc2[i][j][r]);
      }
}

extern "C" void kernel_launch(void* const* d_in, const int* in_sizes, int n_in,
                              void* d_out, int out_size, void* d_ws, size_t ws_size,
                              hipStream_t stream) {
  const float* x  = (const float*)d_in[0];
  const float* Wq = (const float*)d_in[1];
  const float* bq = (const float*)d_in[2];
  const float* Wk = (const float*)d_in[3];
  const float* bk = (const float*)d_in[4];
  const float* Wv = (const float*)d_in[5];
  const float* bv = (const float*)d_in[6];
  const float* Wo = (const float*)d_in[7];
  const float* bo = (const float*)d_in[8];
  float* out = (float*)d_out;

  char* ws = (char*)d_ws;
  unsigned short* xb    = (unsigned short*)(ws + 0);          // 16M elem
  unsigned short* wqkvb = (unsigned short*)(ws + 33554432);   // 3M elem
  unsigned short* wob   = (unsigned short*)(ws + 39845888);   // 1M elem
  unsigned short* qb    = (unsigned short*)(ws + 41943040);   // 16M elem
  unsigned short* kb    = (unsigned short*)(ws + 75497472);   // 16M elem
  unsigned short* vb    = (unsigned short*)(ws + 109051904);  // 16M elem
  unsigned short* out1  = xb;  // reuse: x not needed after projections
  unsigned short* out2  = qb;  // reuse: q not needed after axis-0 retention

  cvt_all<<<dim3(20480), dim3(256), 0, stream>>>(x, Wq, Wk, Wv, Wo, xb, wqkvb, wob);
  gemm_bt<0><<<dim3(128, 24), dim3(256), 0, stream>>>(
      xb, wqkvb, bq, bk, bv, qb, kb, vb, (float*)nullptr);
  retention_fused<<<dim3(128, 16), dim3(256), 0, stream>>>(qb, kb, vb, out1, 0);
  retention_fused<<<dim3(128, 16), dim3(256), 0, stream>>>(out1, kb, vb, out2, 1);
  gemm_bt<1><<<dim3(128, 8), dim3(256), 0, stream>>>(
      out2, wob, bo, nullptr, nullptr, nullptr, nullptr, nullptr, out);
}